// Round 6
// baseline (393.537 us; speedup 1.0000x reference)
//
#include <hip/hip_runtime.h>

#define N_NODES 100000
#define EMB 128
#define NE 800000            // edges per edge set (pos / neg)
#define NEDGES (2 * NE)      // total edges
#define SCAN_ELEMS 1024
#define SCAN_BLOCKS ((N_NODES + SCAN_ELEMS - 1) / SCAN_ELEMS)   // 98

// windowed counting sort for CSR fill
#define NWIN 64
#define WNODES 1563          // 64*1563 = 100032 >= N_NODES
#define ACHUNK 8192
#define ABLOCKS ((NEDGES + ACHUNK - 1) / ACHUNK)                // 196
#define SEGCAP 28000         // per-window record capacity

// ---------------- utility ----------------

__global__ void zero_i32_kernel(int* __restrict__ p, int n) {
    int i = blockIdx.x * blockDim.x + threadIdx.x;
    if (i < n) p[i] = 0;
}

__device__ __forceinline__ unsigned short f2bf(float f) {
    unsigned u = __builtin_bit_cast(unsigned, f);
    u += 0x7FFFu + ((u >> 16) & 1u);          // round-to-nearest-even
    return (unsigned short)(u >> 16);
}

// ---------------- CSR build: degree count ----------------

__global__ void count_kernel(const int* __restrict__ pos_dst,
                             const int* __restrict__ neg_dst,
                             int* __restrict__ cnt) {
    int i = blockIdx.x * blockDim.x + threadIdx.x;
    if (i < NEDGES) {
        int d = (i < NE) ? pos_dst[i] : neg_dst[i - NE];
        atomicAdd(&cnt[d], 1);
    }
}

// block-level exclusive scan, 1024 elems / block (256 thr x 4)
__global__ __launch_bounds__(256) void scan1_kernel(const int* __restrict__ cnt,
                                                    int* __restrict__ rowtmp,
                                                    int* __restrict__ partials) {
    __shared__ int sums[256];
    const int tid  = threadIdx.x;
    const int idx  = blockIdx.x * SCAN_ELEMS + tid * 4;

    int v[4];
    int tsum = 0;
#pragma unroll
    for (int j = 0; j < 4; ++j) {
        int id = idx + j;
        v[j] = (id < N_NODES) ? cnt[id] : 0;
        tsum += v[j];
    }
    sums[tid] = tsum;
    __syncthreads();

    int val = tsum;
    for (int off = 1; off < 256; off <<= 1) {
        int t = (tid >= off) ? sums[tid - off] : 0;
        __syncthreads();
        val += t;
        sums[tid] = val;
        __syncthreads();
    }

    int p = val - tsum;
#pragma unroll
    for (int j = 0; j < 4; ++j) {
        int id = idx + j;
        if (id < N_NODES) rowtmp[id] = p;
        p += v[j];
    }
    if (tid == 255) partials[blockIdx.x] = val;
}

__global__ void scan2_kernel(const int* __restrict__ partials, int* __restrict__ offs) {
    if (threadIdx.x == 0 && blockIdx.x == 0) {
        int run = 0;
        for (int i = 0; i < SCAN_BLOCKS; ++i) { offs[i] = run; run += partials[i]; }
    }
}

__global__ __launch_bounds__(256) void scan3_kernel(const int* __restrict__ rowtmp,
                                                    const int* __restrict__ offs,
                                                    const int* __restrict__ cnt,
                                                    int* __restrict__ rowptr,
                                                    float* __restrict__ dinv) {
    const int off = offs[blockIdx.x];
#pragma unroll
    for (int j = 0; j < 4; ++j) {
        int id = blockIdx.x * SCAN_ELEMS + threadIdx.x + j * 256;
        if (id < N_NODES) {
            rowptr[id] = rowtmp[id] + off;
            dinv[id]   = rsqrtf((float)cnt[id] + 1.0f);  // +1 self-loop
        }
    }
    if (blockIdx.x == 0 && threadIdx.x == 0) rowptr[N_NODES] = NEDGES;
}

__global__ void binit_kernel(const int* __restrict__ rowptr, int* __restrict__ bucket_cursor) {
    int w = threadIdx.x;
    if (w < NWIN) {
        int lo = w * WNODES;
        bucket_cursor[w] = rowptr[(lo < N_NODES) ? lo : N_NODES];
    }
}

// ---- Phase A: bin edges by dst-window, append contiguously per window ----
// temp record: (d - lo) << 17 | src

__global__ __launch_bounds__(256) void binA_kernel(const int* __restrict__ pos,
                                                   const int* __restrict__ neg,
                                                   int* __restrict__ bucket_cursor,
                                                   unsigned* __restrict__ pairs) {
    __shared__ int lcnt[NWIN];
    __shared__ int lofs[NWIN];
    __shared__ int lcur[NWIN];
    __shared__ int gbase[NWIN];
    __shared__ unsigned pbuf[ACHUNK];
    __shared__ unsigned char wbuf[ACHUNK];

    const int tid  = threadIdx.x;
    const int e0   = blockIdx.x * ACHUNK;
    const int ecnt = (NEDGES - e0 < ACHUNK) ? (NEDGES - e0) : ACHUNK;

    if (tid < NWIN) lcnt[tid] = 0;
    __syncthreads();

    for (int k = tid; k < ecnt; k += 256) {
        int i = e0 + k;
        int d = (i < NE) ? pos[NE + i] : neg[i];
        atomicAdd(&lcnt[d / WNODES], 1);
    }
    __syncthreads();

    if (tid == 0) {
        int run = 0;
        for (int w = 0; w < NWIN; ++w) { lofs[w] = run; run += lcnt[w]; }
    }
    __syncthreads();
    if (tid < NWIN) {
        lcur[tid]  = lofs[tid];
        gbase[tid] = atomicAdd(&bucket_cursor[tid], lcnt[tid]);
    }
    __syncthreads();

    for (int k = tid; k < ecnt; k += 256) {
        int i = e0 + k;
        int s, d;
        if (i < NE) { s = pos[i];      d = pos[NE + i]; }
        else        { s = neg[i - NE]; d = neg[i]; }
        int w = d / WNODES;
        unsigned v = ((unsigned)(d - w * WNODES) << 17) | (unsigned)s;
        int lp = atomicAdd(&lcur[w], 1);
        pbuf[lp] = v;
        wbuf[lp] = (unsigned char)w;
    }
    __syncthreads();

    for (int k = tid; k < ecnt; k += 256) {
        int w = wbuf[k];
        pairs[gbase[w] + (k - lofs[w])] = pbuf[k];
    }
}

// ---- Phase B: per-window sort to final CSR order + fuse norm into record ----
// final record: bf16(norm)<<17 | src   (norm = dinv[src]*dinv[dst] in (0,1], sign bit dropped)

__global__ __launch_bounds__(1024) void binB_kernel(const int* __restrict__ rowptr,
                                                    const float* __restrict__ dinv,
                                                    unsigned* __restrict__ pairs) {
    __shared__ unsigned colseg[SEGCAP];   // 112 KB
    __shared__ int lcur[WNODES];          // 6.25 KB
    __shared__ float dinvw[WNODES];       // 6.25 KB

    const int w    = blockIdx.x;
    const int lo   = w * WNODES;
    const int hi   = (lo + WNODES < N_NODES) ? lo + WNODES : N_NODES;
    const int nn   = hi - lo;
    const int base = rowptr[lo];
    const int cntw = rowptr[hi] - base;
    const int tid  = threadIdx.x;

    for (int k = tid; k < nn; k += 1024) {
        lcur[k]  = rowptr[lo + k] - base;
        dinvw[k] = dinv[lo + k];
    }
    __syncthreads();

    for (int k = tid; k < cntw; k += 1024) {
        unsigned v = pairs[base + k];
        int dl = v >> 17;
        int s  = (int)(v & 0x1FFFFu);
        float nrm = dinv[s] * dinvw[dl];
        unsigned u = __builtin_bit_cast(unsigned, nrm);
        unsigned nb = (u + 0x7FFFu + ((u >> 16) & 1u)) >> 16;   // RNE bf16, sign=0 -> 15 bits
        int lp = atomicAdd(&lcur[dl], 1);
        if (lp < SEGCAP) colseg[lp] = (nb << 17) | (unsigned)s;
    }
    __syncthreads();

    for (int k = tid; k < cntw; k += 1024) pairs[base + k] = colseg[k];
}

// ---------------- GEMM: Hb(bf16) = X @ W ----------------

#define TR 32

__global__ __launch_bounds__(256) void gemm_kernel(const float* __restrict__ X,
                                                   const float* __restrict__ W,
                                                   unsigned short* __restrict__ Hb) {
    __shared__ float Xr[TR][EMB + 4];    // 16.9 KiB

    const int tid  = threadIdx.x;
    const int row0 = blockIdx.x * TR;

    for (int i = tid; i < TR * (EMB / 4); i += 256) {
        int r  = i >> 5;
        int k4 = (i & 31) << 2;
        *(float4*)&Xr[r][k4] = *(const float4*)&X[(size_t)(row0 + r) * EMB + k4];
    }
    __syncthreads();

    const int c0 = (tid & 31) * 4;
    const int r0 = (tid >> 5) * 4;

    float acc[4][4];
#pragma unroll
    for (int i = 0; i < 4; ++i)
#pragma unroll
        for (int j = 0; j < 4; ++j) acc[i][j] = 0.0f;

#pragma unroll 2
    for (int k4 = 0; k4 < EMB; k4 += 4) {
        float4 xa0 = *(float4*)&Xr[r0 + 0][k4];
        float4 xa1 = *(float4*)&Xr[r0 + 1][k4];
        float4 xa2 = *(float4*)&Xr[r0 + 2][k4];
        float4 xa3 = *(float4*)&Xr[r0 + 3][k4];
#pragma unroll
        for (int j = 0; j < 4; ++j) {
            float4 w = *(const float4*)&W[(size_t)(k4 + j) * EMB + c0];
            float a0 = (j == 0) ? xa0.x : (j == 1) ? xa0.y : (j == 2) ? xa0.z : xa0.w;
            float a1 = (j == 0) ? xa1.x : (j == 1) ? xa1.y : (j == 2) ? xa1.z : xa1.w;
            float a2 = (j == 0) ? xa2.x : (j == 1) ? xa2.y : (j == 2) ? xa2.z : xa2.w;
            float a3 = (j == 0) ? xa3.x : (j == 1) ? xa3.y : (j == 2) ? xa3.z : xa3.w;
            acc[0][0] += a0 * w.x; acc[0][1] += a0 * w.y; acc[0][2] += a0 * w.z; acc[0][3] += a0 * w.w;
            acc[1][0] += a1 * w.x; acc[1][1] += a1 * w.y; acc[1][2] += a1 * w.z; acc[1][3] += a1 * w.w;
            acc[2][0] += a2 * w.x; acc[2][1] += a2 * w.y; acc[2][2] += a2 * w.z; acc[2][3] += a2 * w.w;
            acc[3][0] += a3 * w.x; acc[3][1] += a3 * w.y; acc[3][2] += a3 * w.z; acc[3][3] += a3 * w.w;
        }
    }

#pragma unroll
    for (int i = 0; i < 4; ++i) {
        ushort4 v;
        v.x = f2bf(acc[i][0]);
        v.y = f2bf(acc[i][1]);
        v.z = f2bf(acc[i][2]);
        v.w = f2bf(acc[i][3]);
        *(ushort4*)&Hb[(size_t)(row0 + r0 + i) * EMB + c0] = v;
    }
}

// ---------------- fused aggregate v2 ----------------
// wave = one node; lane = (sub, dl): sub=lane>>4 covers 4 edges in parallel,
// dl=lane&15 covers dims [dl*8, dl*8+8) via one dwordx4 (4 u32 = 8 bf16).
// Reduce across subs with shfl_xor ^16, ^32; lanes 0..15 write out.

#define AGG_WAVES 4

__global__ __launch_bounds__(256) void aggregate_kernel(const int* __restrict__ rowptr,
                                                        const unsigned* __restrict__ rec,
                                                        const unsigned* __restrict__ Hb32,
                                                        const float* __restrict__ dinv,
                                                        const float* __restrict__ bias,
                                                        float* __restrict__ out) {
    const int wave = threadIdx.x >> 6;
    const int lane = threadIdx.x & 63;
    const int node = blockIdx.x * AGG_WAVES + wave;
    if (node >= N_NODES) return;

    const int sub = lane >> 4;
    const int dl  = lane & 15;

    const int start = rowptr[node];
    const int end   = rowptr[node + 1];

    float acc[8];
#pragma unroll
    for (int j = 0; j < 8; ++j) acc[j] = 0.0f;

    for (int e0 = start; e0 < end; e0 += 4) {
        int eidx  = e0 + sub;
        bool valid = eidx < end;
        int ei = valid ? eidx : end - 1;       // end > start inside loop
        unsigned r = rec[ei];
        int src = (int)(r & 0x1FFFFu);
        float nrm = __builtin_bit_cast(float, (r >> 17) << 16);
        if (!valid) nrm = 0.0f;
        uint4 q = *(const uint4*)&Hb32[(size_t)src * 64 + dl * 4];
        acc[0] += nrm * __builtin_bit_cast(float, q.x << 16);
        acc[1] += nrm * __builtin_bit_cast(float, q.x & 0xFFFF0000u);
        acc[2] += nrm * __builtin_bit_cast(float, q.y << 16);
        acc[3] += nrm * __builtin_bit_cast(float, q.y & 0xFFFF0000u);
        acc[4] += nrm * __builtin_bit_cast(float, q.z << 16);
        acc[5] += nrm * __builtin_bit_cast(float, q.z & 0xFFFF0000u);
        acc[6] += nrm * __builtin_bit_cast(float, q.w << 16);
        acc[7] += nrm * __builtin_bit_cast(float, q.w & 0xFFFF0000u);
    }

#pragma unroll
    for (int j = 0; j < 8; ++j) {
        acc[j] += __shfl_xor(acc[j], 16, 64);
        acc[j] += __shfl_xor(acc[j], 32, 64);
    }

    if (sub == 0) {
        const float dd = dinv[node];
        const float s2 = dd * dd;
        uint4 q = *(const uint4*)&Hb32[(size_t)node * 64 + dl * 4];
        acc[0] += s2 * __builtin_bit_cast(float, q.x << 16);
        acc[1] += s2 * __builtin_bit_cast(float, q.x & 0xFFFF0000u);
        acc[2] += s2 * __builtin_bit_cast(float, q.y << 16);
        acc[3] += s2 * __builtin_bit_cast(float, q.y & 0xFFFF0000u);
        acc[4] += s2 * __builtin_bit_cast(float, q.z << 16);
        acc[5] += s2 * __builtin_bit_cast(float, q.z & 0xFFFF0000u);
        acc[6] += s2 * __builtin_bit_cast(float, q.w << 16);
        acc[7] += s2 * __builtin_bit_cast(float, q.w & 0xFFFF0000u);

        float4 b0 = *(const float4*)&bias[dl * 8];
        float4 b1 = *(const float4*)&bias[dl * 8 + 4];
        float4 o0 = make_float4(acc[0] + b0.x, acc[1] + b0.y, acc[2] + b0.z, acc[3] + b0.w);
        float4 o1 = make_float4(acc[4] + b1.x, acc[5] + b1.y, acc[6] + b1.z, acc[7] + b1.w);
        *(float4*)&out[(size_t)node * EMB + dl * 8]     = o0;
        *(float4*)&out[(size_t)node * EMB + dl * 8 + 4] = o1;
    }
}

// ---------------- launch ----------------

extern "C" void kernel_launch(void* const* d_in, const int* in_sizes, int n_in,
                              void* d_out, int out_size, void* d_ws, size_t ws_size,
                              hipStream_t stream) {
    const float* x  = (const float*)d_in[0];
    const float* W0 = (const float*)d_in[1];
    const float* b0 = (const float*)d_in[2];
    const float* W1 = (const float*)d_in[3];
    const float* b1 = (const float*)d_in[4];
    const int*   pos = (const int*)d_in[5];
    const int*   neg = (const int*)d_in[6];
    float* out = (float*)d_out;

    // workspace layout (4-byte units)
    float* ws      = (float*)d_ws;
    float* dinv    = ws;                            // 100000
    unsigned short* hb = (unsigned short*)(ws + 100352);  // N*128 bf16
    int*   cnt     = (int*)(ws + 6500352);          // 100000
    int*   rowtmp  = (int*)(ws + 6600352);          // 100000
    int*   rowptr  = (int*)(ws + 6700704);          // 100001
    int*   partials= (int*)(ws + 6800708);          // 98
    int*   offs    = (int*)(ws + 6800808);          // 98
    int*   bcur    = (int*)(ws + 6800908);          // 64
    int*   colidx  = (int*)(ws + 6801036);          // 1.6M records

    const int* pos_dst = pos + NE;
    const int* neg_dst = neg + NE;

    // ---- CSR build (shared by both layers) ----
    zero_i32_kernel<<<(N_NODES + 255) / 256, 256, 0, stream>>>(cnt, N_NODES);
    count_kernel<<<(NEDGES + 255) / 256, 256, 0, stream>>>(pos_dst, neg_dst, cnt);
    scan1_kernel<<<SCAN_BLOCKS, 256, 0, stream>>>(cnt, rowtmp, partials);
    scan2_kernel<<<1, 64, 0, stream>>>(partials, offs);
    scan3_kernel<<<SCAN_BLOCKS, 256, 0, stream>>>(rowtmp, offs, cnt, rowptr, dinv);
    binit_kernel<<<1, 64, 0, stream>>>(rowptr, bcur);
    binA_kernel<<<ABLOCKS, 256, 0, stream>>>(pos, neg, bcur, (unsigned*)colidx);
    binB_kernel<<<NWIN, 1024, 0, stream>>>(rowptr, dinv, (unsigned*)colidx);

    // ---- layer 0 ----
    gemm_kernel<<<N_NODES / TR, 256, 0, stream>>>(x, W0, hb);
    aggregate_kernel<<<(N_NODES + AGG_WAVES - 1) / AGG_WAVES, 256, 0, stream>>>(
        rowptr, (const unsigned*)colidx, (const unsigned*)hb, dinv, b0, out);

    // ---- layer 1 ----
    gemm_kernel<<<N_NODES / TR, 256, 0, stream>>>(out, W1, hb);
    aggregate_kernel<<<(N_NODES + AGG_WAVES - 1) / AGG_WAVES, 256, 0, stream>>>(
        rowptr, (const unsigned*)colidx, (const unsigned*)hb, dinv, b1, out);
}

// Round 7
// 380.310 us; speedup vs baseline: 1.0348x; 1.0348x over previous
//
#include <hip/hip_runtime.h>

#define N_NODES 100000
#define EMB 128
#define NE 800000            // edges per edge set (pos / neg)
#define NEDGES (2 * NE)      // total edges
#define SCAN_ELEMS 1024
#define SCAN_BLOCKS ((N_NODES + SCAN_ELEMS - 1) / SCAN_ELEMS)   // 98

// windowed counting sort for CSR fill
#define NWIN 128
#define WNODES 782           // 128*782 = 100096 >= N_NODES
#define ACHUNK 8192
#define ABLOCKS ((NEDGES + ACHUNK - 1) / ACHUNK)                // 196
#define SEGCAP 14000         // per-window record capacity (mean 12512, +13 sigma)

// ---------------- utility ----------------

__global__ void zero_i32_kernel(int* __restrict__ p, int n) {
    int i = blockIdx.x * blockDim.x + threadIdx.x;
    if (i < n) p[i] = 0;
}

__device__ __forceinline__ unsigned short f2bf(float f) {
    unsigned u = __builtin_bit_cast(unsigned, f);
    u += 0x7FFFu + ((u >> 16) & 1u);          // round-to-nearest-even
    return (unsigned short)(u >> 16);
}

// ---------------- CSR build: degree count ----------------

__global__ void count_kernel(const int* __restrict__ pos_dst,
                             const int* __restrict__ neg_dst,
                             int* __restrict__ cnt) {
    int i = blockIdx.x * blockDim.x + threadIdx.x;
    if (i < NEDGES) {
        int d = (i < NE) ? pos_dst[i] : neg_dst[i - NE];
        atomicAdd(&cnt[d], 1);
    }
}

// block-level exclusive scan, 1024 elems / block (256 thr x 4)
__global__ __launch_bounds__(256) void scan1_kernel(const int* __restrict__ cnt,
                                                    int* __restrict__ rowtmp,
                                                    int* __restrict__ partials) {
    __shared__ int sums[256];
    const int tid  = threadIdx.x;
    const int idx  = blockIdx.x * SCAN_ELEMS + tid * 4;

    int v[4];
    int tsum = 0;
#pragma unroll
    for (int j = 0; j < 4; ++j) {
        int id = idx + j;
        v[j] = (id < N_NODES) ? cnt[id] : 0;
        tsum += v[j];
    }
    sums[tid] = tsum;
    __syncthreads();

    int val = tsum;
    for (int off = 1; off < 256; off <<= 1) {
        int t = (tid >= off) ? sums[tid - off] : 0;
        __syncthreads();
        val += t;
        sums[tid] = val;
        __syncthreads();
    }

    int p = val - tsum;
#pragma unroll
    for (int j = 0; j < 4; ++j) {
        int id = idx + j;
        if (id < N_NODES) rowtmp[id] = p;
        p += v[j];
    }
    if (tid == 255) partials[blockIdx.x] = val;
}

__global__ void scan2_kernel(const int* __restrict__ partials, int* __restrict__ offs) {
    if (threadIdx.x == 0 && blockIdx.x == 0) {
        int run = 0;
        for (int i = 0; i < SCAN_BLOCKS; ++i) { offs[i] = run; run += partials[i]; }
    }
}

__global__ __launch_bounds__(256) void scan3_kernel(const int* __restrict__ rowtmp,
                                                    const int* __restrict__ offs,
                                                    const int* __restrict__ cnt,
                                                    int* __restrict__ rowptr,
                                                    float* __restrict__ dinv) {
    const int off = offs[blockIdx.x];
#pragma unroll
    for (int j = 0; j < 4; ++j) {
        int id = blockIdx.x * SCAN_ELEMS + threadIdx.x + j * 256;
        if (id < N_NODES) {
            rowptr[id] = rowtmp[id] + off;
            dinv[id]   = rsqrtf((float)cnt[id] + 1.0f);  // +1 self-loop
        }
    }
    if (blockIdx.x == 0 && threadIdx.x == 0) rowptr[N_NODES] = NEDGES;
}

__global__ void binit_kernel(const int* __restrict__ rowptr, int* __restrict__ bucket_cursor) {
    int w = threadIdx.x;
    if (w < NWIN) {
        int lo = w * WNODES;
        bucket_cursor[w] = rowptr[(lo < N_NODES) ? lo : N_NODES];
    }
}

// ---- Phase A: bin edges by dst-window, append contiguously per window ----
// temp record: (d - lo) << 17 | src

__global__ __launch_bounds__(256) void binA_kernel(const int* __restrict__ pos,
                                                   const int* __restrict__ neg,
                                                   int* __restrict__ bucket_cursor,
                                                   unsigned* __restrict__ pairs) {
    __shared__ int lcnt[NWIN];
    __shared__ int lofs[NWIN];
    __shared__ int lcur[NWIN];
    __shared__ int gbase[NWIN];
    __shared__ unsigned pbuf[ACHUNK];
    __shared__ unsigned char wbuf[ACHUNK];

    const int tid  = threadIdx.x;
    const int e0   = blockIdx.x * ACHUNK;
    const int ecnt = (NEDGES - e0 < ACHUNK) ? (NEDGES - e0) : ACHUNK;

    if (tid < NWIN) lcnt[tid] = 0;
    __syncthreads();

    for (int k = tid; k < ecnt; k += 256) {
        int i = e0 + k;
        int d = (i < NE) ? pos[NE + i] : neg[i];
        atomicAdd(&lcnt[d / WNODES], 1);
    }
    __syncthreads();

    if (tid == 0) {
        int run = 0;
        for (int w = 0; w < NWIN; ++w) { lofs[w] = run; run += lcnt[w]; }
    }
    __syncthreads();
    if (tid < NWIN) {
        lcur[tid]  = lofs[tid];
        gbase[tid] = atomicAdd(&bucket_cursor[tid], lcnt[tid]);
    }
    __syncthreads();

    for (int k = tid; k < ecnt; k += 256) {
        int i = e0 + k;
        int s, d;
        if (i < NE) { s = pos[i];      d = pos[NE + i]; }
        else        { s = neg[i - NE]; d = neg[i]; }
        int w = d / WNODES;
        unsigned v = ((unsigned)(d - w * WNODES) << 17) | (unsigned)s;
        int lp = atomicAdd(&lcur[w], 1);
        pbuf[lp] = v;
        wbuf[lp] = (unsigned char)w;
    }
    __syncthreads();

    for (int k = tid; k < ecnt; k += 256) {
        int w = wbuf[k];
        pairs[gbase[w] + (k - lofs[w])] = pbuf[k];
    }
}

// ---- Phase B: per-window sort to final CSR order + fuse norm into record ----
// final record: bf16(norm)<<17 | src   (norm = dinv[src]*dinv[dst] in (0,1], sign bit dropped)

__global__ __launch_bounds__(1024) void binB_kernel(const int* __restrict__ rowptr,
                                                    const float* __restrict__ dinv,
                                                    unsigned* __restrict__ pairs) {
    __shared__ unsigned colseg[SEGCAP];   // 56 KB
    __shared__ int lcur[WNODES];          // 3.1 KB
    __shared__ float dinvw[WNODES];       // 3.1 KB

    const int w    = blockIdx.x;
    const int lo   = w * WNODES;
    const int hi   = (lo + WNODES < N_NODES) ? lo + WNODES : N_NODES;
    const int nn   = hi - lo;
    const int base = rowptr[lo];
    const int cntw = rowptr[hi] - base;
    const int tid  = threadIdx.x;

    for (int k = tid; k < nn; k += 1024) {
        lcur[k]  = rowptr[lo + k] - base;
        dinvw[k] = dinv[lo + k];
    }
    __syncthreads();

    for (int k = tid; k < cntw; k += 1024) {
        unsigned v = pairs[base + k];
        int dl = v >> 17;
        int s  = (int)(v & 0x1FFFFu);
        float nrm = dinv[s] * dinvw[dl];
        unsigned u = __builtin_bit_cast(unsigned, nrm);
        unsigned nb = (u + 0x7FFFu + ((u >> 16) & 1u)) >> 16;   // RNE bf16, sign=0 -> 15 bits
        int lp = atomicAdd(&lcur[dl], 1);
        if (lp < SEGCAP) colseg[lp] = (nb << 17) | (unsigned)s;
    }
    __syncthreads();

    for (int k = tid; k < cntw; k += 1024) pairs[base + k] = colseg[k];
}

// ---------------- GEMM: Hb(bf16) = X @ W  (TR=64, 8 rows/thread) ----------------

#define TR 64

__global__ __launch_bounds__(256) void gemm_kernel(const float* __restrict__ X,
                                                   const float* __restrict__ W,
                                                   unsigned short* __restrict__ Hb) {
    __shared__ float Xr[TR][EMB + 4];    // 64 x 132 f = 33.8 KiB

    const int tid  = threadIdx.x;
    const int row0 = blockIdx.x * TR;

    // stage X tile: 64 rows x 32 float4 (clamped for tail block)
    for (int i = tid; i < TR * (EMB / 4); i += 256) {
        int r  = i >> 5;
        int k4 = (i & 31) << 2;
        int rr = row0 + r;
        if (rr >= N_NODES) rr = N_NODES - 1;
        *(float4*)&Xr[r][k4] = *(const float4*)&X[(size_t)rr * EMB + k4];
    }
    __syncthreads();

    const int c0 = (tid & 31) * 4;   // output col group
    const int r0 = (tid >> 5) * 8;   // 8 rows per thread

    float acc[8][4];
#pragma unroll
    for (int i = 0; i < 8; ++i)
#pragma unroll
        for (int j = 0; j < 4; ++j) acc[i][j] = 0.0f;

#pragma unroll 4
    for (int k4 = 0; k4 < EMB; k4 += 4) {
        float4 w0 = *(const float4*)&W[(size_t)(k4 + 0) * EMB + c0];
        float4 w1 = *(const float4*)&W[(size_t)(k4 + 1) * EMB + c0];
        float4 w2 = *(const float4*)&W[(size_t)(k4 + 2) * EMB + c0];
        float4 w3 = *(const float4*)&W[(size_t)(k4 + 3) * EMB + c0];
#pragma unroll
        for (int i = 0; i < 8; ++i) {
            float4 xa = *(float4*)&Xr[r0 + i][k4];
            acc[i][0] += xa.x * w0.x + xa.y * w1.x + xa.z * w2.x + xa.w * w3.x;
            acc[i][1] += xa.x * w0.y + xa.y * w1.y + xa.z * w2.y + xa.w * w3.y;
            acc[i][2] += xa.x * w0.z + xa.y * w1.z + xa.z * w2.z + xa.w * w3.z;
            acc[i][3] += xa.x * w0.w + xa.y * w1.w + xa.z * w2.w + xa.w * w3.w;
        }
    }

#pragma unroll
    for (int i = 0; i < 8; ++i) {
        int rr = row0 + r0 + i;
        if (rr < N_NODES) {
            ushort4 v;
            v.x = f2bf(acc[i][0]);
            v.y = f2bf(acc[i][1]);
            v.z = f2bf(acc[i][2]);
            v.w = f2bf(acc[i][3]);
            *(ushort4*)&Hb[(size_t)rr * EMB + c0] = v;
        }
    }
}

// ---------------- fused aggregate ----------------
// wave = one node; lane = (sub, dl): sub=lane>>4 covers 4 edges in parallel,
// dl=lane&15 covers dims [dl*8, dl*8+8) via one dwordx4 (4 u32 = 8 bf16).
// Reduce across subs with shfl_xor ^16, ^32; lanes 0..15 write out.

#define AGG_WAVES 4

__global__ __launch_bounds__(256) void aggregate_kernel(const int* __restrict__ rowptr,
                                                        const unsigned* __restrict__ rec,
                                                        const unsigned* __restrict__ Hb32,
                                                        const float* __restrict__ dinv,
                                                        const float* __restrict__ bias,
                                                        float* __restrict__ out) {
    const int wave = threadIdx.x >> 6;
    const int lane = threadIdx.x & 63;
    const int node = blockIdx.x * AGG_WAVES + wave;
    if (node >= N_NODES) return;

    const int sub = lane >> 4;
    const int dl  = lane & 15;

    const int start = rowptr[node];
    const int end   = rowptr[node + 1];

    float acc[8];
#pragma unroll
    for (int j = 0; j < 8; ++j) acc[j] = 0.0f;

    for (int e0 = start; e0 < end; e0 += 4) {
        int eidx  = e0 + sub;
        bool valid = eidx < end;
        int ei = valid ? eidx : end - 1;
        unsigned r = rec[ei];
        int src = (int)(r & 0x1FFFFu);
        float nrm = __builtin_bit_cast(float, (r >> 17) << 16);
        if (!valid) nrm = 0.0f;
        uint4 q = *(const uint4*)&Hb32[(size_t)src * 64 + dl * 4];
        acc[0] += nrm * __builtin_bit_cast(float, q.x << 16);
        acc[1] += nrm * __builtin_bit_cast(float, q.x & 0xFFFF0000u);
        acc[2] += nrm * __builtin_bit_cast(float, q.y << 16);
        acc[3] += nrm * __builtin_bit_cast(float, q.y & 0xFFFF0000u);
        acc[4] += nrm * __builtin_bit_cast(float, q.z << 16);
        acc[5] += nrm * __builtin_bit_cast(float, q.z & 0xFFFF0000u);
        acc[6] += nrm * __builtin_bit_cast(float, q.w << 16);
        acc[7] += nrm * __builtin_bit_cast(float, q.w & 0xFFFF0000u);
    }

#pragma unroll
    for (int j = 0; j < 8; ++j) {
        acc[j] += __shfl_xor(acc[j], 16, 64);
        acc[j] += __shfl_xor(acc[j], 32, 64);
    }

    if (sub == 0) {
        const float dd = dinv[node];
        const float s2 = dd * dd;
        uint4 q = *(const uint4*)&Hb32[(size_t)node * 64 + dl * 4];
        acc[0] += s2 * __builtin_bit_cast(float, q.x << 16);
        acc[1] += s2 * __builtin_bit_cast(float, q.x & 0xFFFF0000u);
        acc[2] += s2 * __builtin_bit_cast(float, q.y << 16);
        acc[3] += s2 * __builtin_bit_cast(float, q.y & 0xFFFF0000u);
        acc[4] += s2 * __builtin_bit_cast(float, q.z << 16);
        acc[5] += s2 * __builtin_bit_cast(float, q.z & 0xFFFF0000u);
        acc[6] += s2 * __builtin_bit_cast(float, q.w << 16);
        acc[7] += s2 * __builtin_bit_cast(float, q.w & 0xFFFF0000u);

        float4 b0 = *(const float4*)&bias[dl * 8];
        float4 b1 = *(const float4*)&bias[dl * 8 + 4];
        float4 o0 = make_float4(acc[0] + b0.x, acc[1] + b0.y, acc[2] + b0.z, acc[3] + b0.w);
        float4 o1 = make_float4(acc[4] + b1.x, acc[5] + b1.y, acc[6] + b1.z, acc[7] + b1.w);
        *(float4*)&out[(size_t)node * EMB + dl * 8]     = o0;
        *(float4*)&out[(size_t)node * EMB + dl * 8 + 4] = o1;
    }
}

// ---------------- launch ----------------

extern "C" void kernel_launch(void* const* d_in, const int* in_sizes, int n_in,
                              void* d_out, int out_size, void* d_ws, size_t ws_size,
                              hipStream_t stream) {
    const float* x  = (const float*)d_in[0];
    const float* W0 = (const float*)d_in[1];
    const float* b0 = (const float*)d_in[2];
    const float* W1 = (const float*)d_in[3];
    const float* b1 = (const float*)d_in[4];
    const int*   pos = (const int*)d_in[5];
    const int*   neg = (const int*)d_in[6];
    float* out = (float*)d_out;

    // workspace layout (4-byte units)
    float* ws      = (float*)d_ws;
    float* dinv    = ws;                            // 100000
    unsigned short* hb = (unsigned short*)(ws + 100352);  // N*128 bf16
    int*   cnt     = (int*)(ws + 6500352);          // 100000
    int*   rowtmp  = (int*)(ws + 6600352);          // 100000
    int*   rowptr  = (int*)(ws + 6700704);          // 100001
    int*   partials= (int*)(ws + 6800708);          // 98
    int*   offs    = (int*)(ws + 6800808);          // 98
    int*   bcur    = (int*)(ws + 6800908);          // 128
    int*   colidx  = (int*)(ws + 6801100);          // 1.6M records

    const int* pos_dst = pos + NE;
    const int* neg_dst = neg + NE;

    // ---- CSR build (shared by both layers) ----
    zero_i32_kernel<<<(N_NODES + 255) / 256, 256, 0, stream>>>(cnt, N_NODES);
    count_kernel<<<(NEDGES + 255) / 256, 256, 0, stream>>>(pos_dst, neg_dst, cnt);
    scan1_kernel<<<SCAN_BLOCKS, 256, 0, stream>>>(cnt, rowtmp, partials);
    scan2_kernel<<<1, 64, 0, stream>>>(partials, offs);
    scan3_kernel<<<SCAN_BLOCKS, 256, 0, stream>>>(rowtmp, offs, cnt, rowptr, dinv);
    binit_kernel<<<1, NWIN, 0, stream>>>(rowptr, bcur);
    binA_kernel<<<ABLOCKS, 256, 0, stream>>>(pos, neg, bcur, (unsigned*)colidx);
    binB_kernel<<<NWIN, 1024, 0, stream>>>(rowptr, dinv, (unsigned*)colidx);

    // ---- layer 0 ----
    gemm_kernel<<<(N_NODES + TR - 1) / TR, 256, 0, stream>>>(x, W0, hb);
    aggregate_kernel<<<(N_NODES + AGG_WAVES - 1) / AGG_WAVES, 256, 0, stream>>>(
        rowptr, (const unsigned*)colidx, (const unsigned*)hb, dinv, b0, out);

    // ---- layer 1 ----
    gemm_kernel<<<(N_NODES + TR - 1) / TR, 256, 0, stream>>>(out, W1, hb);
    aggregate_kernel<<<(N_NODES + AGG_WAVES - 1) / AGG_WAVES, 256, 0, stream>>>(
        rowptr, (const unsigned*)colidx, (const unsigned*)hb, dinv, b1, out);
}